// Round 20
// baseline (6055.346 us; speedup 1.0000x reference)
//
#include <hip/hip_runtime.h>
#include <hip/hip_fp16.h>

#define HF 192

static inline int divup(int a, int b){ return (a+b-1)/b; }

typedef _Float16 half8 __attribute__((ext_vector_type(8)));
typedef float f32x4 __attribute__((ext_vector_type(4)));

// ---- static device workspace, 195,734,272 B ----
#define G_WS_BYTES 195734272ull
__device__ __align__(256) char g_ws[G_WS_BYTES];

// fp16 node buffers (up to n=160000)
#define OFF_HH    0ull
#define OFF_T1H   61440000ull
#define OFF_T2H   122880000ull
// CSR / small buffers
#define OFF_DEG  184320000ull
#define OFF_RP   184960000ull
#define OFF_COL  185600032ull
#define OFF_NRM  189440032ull
#define OFF_O1F  190080032ull
#define OFF_U1F  190200032ull
#define OFF_O2F  190680032ull
#define OFF_U2F  191160032ull
#define OFF_WT   193080032ull   // 12 layers x [192 cols][576 k] fp16
// fp32 dim-3 temps alias the (not-yet-live) T1H region
#define OFF_X1F  OFF_T1H
#define OFF_X2F  (OFF_T1H + 1920000ull)

__device__ __forceinline__ float*  wsf(unsigned long long o){ return (float*) (g_ws + o); }
__device__ __forceinline__ int*    wsi(unsigned long long o){ return (int*)   (g_ws + o); }
__device__ __forceinline__ __half* wsh(unsigned long long o){ return (__half*)(g_ws + o); }

// ---------------- utility ----------------
__global__ void k_zero(unsigned long long off, int n) {
  int i = blockIdx.x*blockDim.x + threadIdx.x;
  if (i < n) wsi(off)[i] = 0;
}
__global__ void k_copyi(unsigned long long aOff, unsigned long long bOff, int n) {
  int i = blockIdx.x*blockDim.x + threadIdx.x;
  if (i < n) wsi(bOff)[i] = wsi(aOff)[i];
}

// ---------------- CSR build ----------------
__global__ void k_count_direct(const int* __restrict__ dst, int E) {
  int* deg = wsi(OFF_DEG);
  int e = blockIdx.x*blockDim.x + threadIdx.x;
  if (e < E) atomicAdd(&deg[dst[e]], 1);
}
__global__ void k_count_bidir(const int* __restrict__ edge, int E) {
  int* deg = wsi(OFF_DEG);
  int e = blockIdx.x*blockDim.x + threadIdx.x;
  if (e < E) {
    atomicAdd(&deg[edge[2*e+1]], 1);
    atomicAdd(&deg[edge[2*e  ]], 1);
  }
}
__global__ void k_norm(int n) {
  const int* deg = wsi(OFF_DEG);
  float* nrm = wsf(OFF_NRM);
  int i = blockIdx.x*blockDim.x + threadIdx.x;
  if (i < n) {
    int d = deg[i]; if (d < 1) d = 1;
    nrm[i] = rsqrtf((float)d);
  }
}
__global__ __launch_bounds__(1024) void k_exscan(int n) {
  const int* in = wsi(OFF_DEG);
  int* out = wsi(OFF_RP);
  __shared__ int sm[1024];
  int t = threadIdx.x;
  int carry = 0;
  for (int base = 0; base < n; base += 4096) {
    int idx = base + t*4;
    int v0 = (idx+0 < n) ? in[idx+0] : 0;
    int v1 = (idx+1 < n) ? in[idx+1] : 0;
    int v2 = (idx+2 < n) ? in[idx+2] : 0;
    int v3 = (idx+3 < n) ? in[idx+3] : 0;
    int s = v0+v1+v2+v3;
    sm[t] = s;
    __syncthreads();
    for (int off = 1; off < 1024; off <<= 1) {
      int u = (t >= off) ? sm[t-off] : 0;
      __syncthreads();
      sm[t] += u;
      __syncthreads();
    }
    int excl = carry + sm[t] - s;
    if (idx   < n) out[idx]   = excl;
    if (idx+1 < n) out[idx+1] = excl + v0;
    if (idx+2 < n) out[idx+2] = excl + v0+v1;
    if (idx+3 < n) out[idx+3] = excl + v0+v1+v2;
    carry += sm[1023];
    __syncthreads();
  }
  if (t == 0) out[n] = carry;
}
__global__ void k_fill_direct(const int* __restrict__ src, const int* __restrict__ dst, int E) {
  int* cur = wsi(OFF_DEG);
  int* col = wsi(OFF_COL);
  int e = blockIdx.x*blockDim.x + threadIdx.x;
  if (e < E) {
    int p = atomicAdd(&cur[dst[e]], 1);
    col[p] = src[e];
  }
}
__global__ void k_fill_bidir(const int* __restrict__ edge, int E) {
  int* cur = wsi(OFF_DEG);
  int* col = wsi(OFF_COL);
  int e = blockIdx.x*blockDim.x + threadIdx.x;
  if (e < E) {
    int u = edge[2*e], v = edge[2*e+1];
    int p = atomicAdd(&cur[v], 1); col[p] = u;
    int q = atomicAdd(&cur[u], 1); col[q] = v;
  }
}

// ---------------- propagation dim-3 (f32) ----------------
__global__ void k_spmm3(const float* __restrict__ Xext, unsigned long long Xoff,
                        unsigned long long Yoff, int n) {
  const float* X = Xext ? Xext : wsf(Xoff);
  float* Y = wsf(Yoff);
  const int* rowptr = wsi(OFF_RP);
  const int* col = wsi(OFF_COL);
  const float* nrm = wsf(OFF_NRM);
  int row = blockIdx.x*blockDim.x + threadIdx.x;
  if (row >= n) return;
  int s = rowptr[row], e = rowptr[row+1];
  float a0=0.f, a1=0.f, a2=0.f;
  for (int i = s; i < e; ++i) {
    int c = col[i]; float v = nrm[c];
    a0 = fmaf(v, X[c*3+0], a0);
    a1 = fmaf(v, X[c*3+1], a1);
    a2 = fmaf(v, X[c*3+2], a2);
  }
  float nm = nrm[row];
  Y[row*3+0] = a0*nm; Y[row*3+1] = a1*nm; Y[row*3+2] = a2*nm;
}

// ---------------- fp16 SpMM, half8 per lane, 24 lanes/row, 2-edge unrolled ----------------
__global__ __launch_bounds__(192) void k_spmm8(unsigned long long Xoff,
                                               unsigned long long Yoff, int n) {
  int gid = blockIdx.x*192 + threadIdx.x;
  if (gid >= n*24) return;
  int row = gid / 24, f8 = gid - row*24;
  const half8* __restrict__ X8 = (const half8*)wsh(Xoff);
  half8* __restrict__ Y8 = (half8*)wsh(Yoff);
  const int* rowptr = wsi(OFF_RP);
  const int* col = wsi(OFF_COL);
  const float* nrm = wsf(OFF_NRM);
  int s = rowptr[row], e = rowptr[row+1];
  float acc0[8], acc1[8];
  #pragma unroll
  for (int j = 0; j < 8; ++j) { acc0[j] = 0.f; acc1[j] = 0.f; }
  int i = s;
  for (; i + 2 <= e; i += 2) {
    int c0 = col[i], c1 = col[i+1];
    float w0 = nrm[c0], w1 = nrm[c1];
    half8 v0 = X8[(size_t)c0*24 + f8];
    half8 v1 = X8[(size_t)c1*24 + f8];
    #pragma unroll
    for (int j = 0; j < 8; ++j) {
      acc0[j] = fmaf(w0, (float)v0[j], acc0[j]);
      acc1[j] = fmaf(w1, (float)v1[j], acc1[j]);
    }
  }
  if (i < e) {
    int c0 = col[i];
    float w0 = nrm[c0];
    half8 v0 = X8[(size_t)c0*24 + f8];
    #pragma unroll
    for (int j = 0; j < 8; ++j) acc0[j] = fmaf(w0, (float)v0[j], acc0[j]);
  }
  float nm = nrm[row];
  half8 r;
  #pragma unroll
  for (int j = 0; j < 8; ++j) r[j] = (_Float16)((acc0[j] + acc1[j])*nm);
  Y8[(size_t)row*24 + f8] = r;
}

// ---------------- first layer: [x|x1|x2](n,9)@Wf + b, relu -> H fp16 ----------------
__global__ void k_gemm_first(const float* __restrict__ xext, unsigned long long xOff,
                             const float* __restrict__ W, const float* __restrict__ b, int n) {
  const float* x  = xext ? xext : wsf(xOff);
  const float* x1 = wsf(OFF_X1F);
  const float* x2 = wsf(OFF_X2F);
  __half* H = wsh(OFF_HH);
  int idx = blockIdx.x*blockDim.x + threadIdx.x;
  if (idx >= n*HF) return;
  int row = idx / HF, c = idx - row*HF;
  float acc = b[c];
  #pragma unroll
  for (int k = 0; k < 3; ++k) acc = fmaf(x [row*3+k], W[(0+k)*HF + c], acc);
  #pragma unroll
  for (int k = 0; k < 3; ++k) acc = fmaf(x1[row*3+k], W[(3+k)*HF + c], acc);
  #pragma unroll
  for (int k = 0; k < 3; ++k) acc = fmaf(x2[row*3+k], W[(6+k)*HF + c], acc);
  H[idx] = __float2half(fmaxf(acc, 0.f));
}

// ---------------- W prep: Wt[it][col][k] = fp16(Wm[stage it][k][col]) ----------------
__global__ void k_wprep(const float* __restrict__ Wm, int s) {
  int idx = blockIdx.x*blockDim.x + threadIdx.x;
  if (idx >= 12*576*HF) return;
  int it = idx / (576*HF);
  int rem = idx - it*576*HF;
  int k = rem / HF;
  int c = rem - k*HF;
  wsh(OFF_WT)[(size_t)it*HF*576 + (size_t)c*576 + k] =
      __float2half(Wm[((size_t)(s*12+it)*576 + k)*HF + c]);
}

// ---------------- MFMA mid layer, 128 rows/block, LDS-staged B ----------------
// H = f(H@W0 + T1@W1 + T2@W2 + b); 4 waves x (2 x 16-row A-frags)
#define BPAD 104
__global__ __launch_bounds__(256,4) void k_mfma_mid(
    const float* __restrict__ b, int it, int n, int residual)
{
  __half* __restrict__ H = wsh(OFF_HH);
  const __half* __restrict__ T1 = wsh(OFF_T1H);
  const __half* __restrict__ T2 = wsh(OFF_T2H);
  const __half* __restrict__ Wt = wsh(OFF_WT) + (size_t)it*HF*576;
  __shared__ _Float16 Bs[192*BPAD];   // 39,936 B
  int t = threadIdx.x;
  int w = t >> 6;
  int l = t & 63;
  int lr = l & 15;
  int lg = l >> 4;
  int row0 = blockIdx.x*128 + w*32;

  f32x4 acc[2][12];
  #pragma unroll
  for (int s2 = 0; s2 < 2; ++s2)
    #pragma unroll
    for (int i = 0; i < 12; ++i) acc[s2][i] = (f32x4){0.f,0.f,0.f,0.f};

  const __half* Xp[3] = { H, T1, T2 };
  for (int p = 0; p < 3; ++p) {
    const __half* X = Xp[p];
    for (int kh = 0; kh < 2; ++kh) {
      __syncthreads();
      for (int i = t; i < 192*12; i += 256) {
        int c  = i / 12;
        int k8 = i - c*12;
        *(half8*)&Bs[c*BPAD + k8*8] =
            *(const half8*)&Wt[(size_t)c*576 + p*HF + kh*96 + k8*8];
      }
      __syncthreads();
      #pragma unroll
      for (int k0 = 0; k0 < 96; k0 += 32) {
        half8 a0 = *(const half8*)&X[(size_t)(row0 + lr     )*HF + kh*96 + k0 + lg*8];
        half8 a1 = *(const half8*)&X[(size_t)(row0 + 16 + lr)*HF + kh*96 + k0 + lg*8];
        #pragma unroll
        for (int tl = 0; tl < 12; ++tl) {
          half8 bb = *(const half8*)&Bs[(tl*16 + lr)*BPAD + k0 + lg*8];
          acc[0][tl] = __builtin_amdgcn_mfma_f32_16x16x32_f16(a0, bb, acc[0][tl], 0, 0, 0);
          acc[1][tl] = __builtin_amdgcn_mfma_f32_16x16x32_f16(a1, bb, acc[1][tl], 0, 0, 0);
        }
      }
    }
  }

  #pragma unroll
  for (int s2 = 0; s2 < 2; ++s2) {
    #pragma unroll
    for (int tl = 0; tl < 12; ++tl) {
      int c = tl*16 + lr;
      float bias = b[c];
      #pragma unroll
      for (int j = 0; j < 4; ++j) {
        int row = row0 + s2*16 + lg*4 + j;
        if (row < n) {
          size_t o = (size_t)row*HF + c;
          float cur = fmaxf(acc[s2][tl][j] + bias, 0.f);
          float h = cur;
          if (residual) h = 0.5f*(__half2float(H[o]) + cur);
          H[o] = __float2half(h);
        }
      }
    }
  }
}

// ---------------- last layer (vectorized linear reads) ----------------
__global__ void k_last_lin(const float* __restrict__ W, const float* __restrict__ b,
                           float* __restrict__ outb, unsigned long long outfOff,
                           int hasOutf, int n) {
  int row = blockIdx.x*blockDim.x + threadIdx.x;
  if (row >= n) return;
  const __half* bufs[3] = { wsh(OFF_HH), wsh(OFF_T1H), wsh(OFF_T2H) };
  float a0 = b[0], a1 = b[1], a2 = b[2];
  for (int p = 0; p < 3; ++p) {
    const half8* x8 = (const half8*)&bufs[p][(size_t)row*HF];
    #pragma unroll 4
    for (int k8 = 0; k8 < 24; ++k8) {
      half8 v = x8[k8];
      #pragma unroll
      for (int j = 0; j < 8; ++j) {
        int k = k8*8 + j;
        const float* w = &W[(p*HF + k)*3];
        float vv = (float)v[j];
        a0 = fmaf(vv, w[0], a0); a1 = fmaf(vv, w[1], a1); a2 = fmaf(vv, w[2], a2);
      }
    }
  }
  outb[row*3+0] = a0;
  outb[row*3+1] = a1;
  outb[row*3+2] = a2;
  if (hasOutf) {
    float* outf = wsf(outfOff);
    outf[row*3+0] = a0; outf[row*3+1] = a1; outf[row*3+2] = a2;
  }
}

// ---------------- unpool ----------------
__global__ void k_unpool(unsigned long long srcOff, const int* __restrict__ pidx,
                         unsigned long long dstfOff, float* __restrict__ dstb,
                         int n, int P) {
  const float* src = wsf(srcOff);
  float* dstf = wsf(dstfOff);
  int i = blockIdx.x*blockDim.x + threadIdx.x;
  if (i >= n + P) return;
  float v0, v1, v2;
  if (i < n) {
    v0 = src[i*3+0]; v1 = src[i*3+1]; v2 = src[i*3+2];
  } else {
    int a = pidx[(i-n)*2], c = pidx[(i-n)*2+1];
    v0 = 0.5f*(src[a*3+0] + src[c*3+0]);
    v1 = 0.5f*(src[a*3+1] + src[c*3+1]);
    v2 = 0.5f*(src[a*3+2] + src[c*3+2]);
  }
  dstf[i*3+0] = v0; dstf[i*3+1] = v1; dstf[i*3+2] = v2;
  dstb[i*3+0] = v0;
  dstb[i*3+1] = v1;
  dstb[i*3+2] = v2;
}

extern "C" void kernel_launch(void* const* d_in, const int* in_sizes, int n_in,
                              void* d_out, int out_size, void* d_ws, size_t ws_size,
                              hipStream_t stream) {
  (void)in_sizes; (void)n_in; (void)out_size; (void)d_ws; (void)ws_size;
  const float* features = (const float*)d_in[0];
  const int*  src0  = (const int*)d_in[1];
  const int*  dst0  = (const int*)d_in[2];
  const int*  pool0 = (const int*)d_in[3];
  const int*  edge0 = (const int*)d_in[4];
  const int*  pool1 = (const int*)d_in[5];
  const int*  edge1 = (const int*)d_in[6];
  const float* Wf = (const float*)d_in[7];
  const float* bfp = (const float*)d_in[8];
  const float* Wm = (const float*)d_in[9];
  const float* bm = (const float*)d_in[10];
  const float* Wl = (const float*)d_in[11];
  const float* bl = (const float*)d_in[12];
  float* out = (float*)d_out;

  auto csr = [&](int n, const int* srcD, const int* dstD, int Edir,
                 const int* edgeB, int Eund) {
    k_zero<<<divup(n,256),256,0,stream>>>(OFF_DEG, n);
    if (srcD) k_count_direct<<<divup(Edir,256),256,0,stream>>>(dstD, Edir);
    else      k_count_bidir <<<divup(Eund,256),256,0,stream>>>(edgeB, Eund);
    k_norm<<<divup(n,256),256,0,stream>>>(n);
    k_exscan<<<1,1024,0,stream>>>(n);
    k_copyi<<<divup(n,256),256,0,stream>>>(OFF_RP, OFF_DEG, n);
    if (srcD) k_fill_direct<<<divup(Edir,256),256,0,stream>>>(srcD, dstD, Edir);
    else      k_fill_bidir <<<divup(Eund,256),256,0,stream>>>(edgeB, Eund);
  };

  auto stage_u = [&](const float* xext, unsigned long long xOff, int n,
                     const int* srcD, const int* dstD, int Edir,
                     const int* edgeB, int Eund,
                     int s, float* outb, unsigned long long outfOff, int hasOutf) {
    csr(n, srcD, dstD, Edir, edgeB, Eund);
    k_wprep<<<divup(12*576*HF,256),256,0,stream>>>(Wm, s);
    k_spmm3<<<divup(n,256),256,0,stream>>>(xext, xOff, OFF_X1F, n);
    k_spmm3<<<divup(n,256),256,0,stream>>>(nullptr, OFF_X1F, OFF_X2F, n);
    k_gemm_first<<<divup(n*HF,256),256,0,stream>>>(xext, xOff,
        Wf + (size_t)s*9*HF, bfp + s*HF, n);
    int gsp = divup(n*24,192);
    for (int it = 0; it < 12; ++it) {
      k_spmm8<<<gsp,192,0,stream>>>(OFF_HH,  OFF_T1H, n);
      k_spmm8<<<gsp,192,0,stream>>>(OFF_T1H, OFF_T2H, n);
      k_mfma_mid<<<divup(n,128),256,0,stream>>>(bm + (s*12+it)*HF, it, n,
          ((it+1)%2==0) ? 1 : 0);
    }
    k_spmm8<<<gsp,192,0,stream>>>(OFF_HH,  OFF_T1H, n);
    k_spmm8<<<gsp,192,0,stream>>>(OFF_T1H, OFF_T2H, n);
    k_last_lin<<<divup(n,256),256,0,stream>>>(Wl + (size_t)s*576*3, bl + s*3,
        outb, outfOff, hasOutf, n);
  };

  // stage 1: n=10000, direct edges
  stage_u(features, 0ull, 10000, src0, dst0, 60000, nullptr, 0,
          0, out + 0, OFF_O1F, 1);
  k_unpool<<<divup(40000,256),256,0,stream>>>(OFF_O1F, pool0, OFF_U1F, out + 630000, 10000, 30000);
  // stage 2: n=40000, bidir edge0
  stage_u(nullptr, OFF_U1F, 40000, nullptr, nullptr, 0, edge0, 120000,
          1, out + 30000, OFF_O2F, 1);
  k_unpool<<<divup(160000,256),256,0,stream>>>(OFF_O2F, pool1, OFF_U2F, out + 750000, 40000, 120000);
  // stage 3: n=160000, bidir edge1
  stage_u(nullptr, OFF_U2F, 160000, nullptr, nullptr, 0, edge1, 480000,
          2, out + 150000, OFF_O1F, 0);
}

// Round 21
// 5519.033 us; speedup vs baseline: 1.0972x; 1.0972x over previous
//
#include <hip/hip_runtime.h>
#include <hip/hip_fp16.h>

#define HF 192

static inline int divup(int a, int b){ return (a+b-1)/b; }

typedef _Float16 half8 __attribute__((ext_vector_type(8)));
typedef float f32x4 __attribute__((ext_vector_type(4)));

// ---- static device workspace, 195,734,272 B ----
#define G_WS_BYTES 195734272ull
__device__ __align__(256) char g_ws[G_WS_BYTES];

// fp16 node buffers (up to n=160000)
#define OFF_HH    0ull
#define OFF_T1H   61440000ull
#define OFF_T2H   122880000ull
// CSR / small buffers
#define OFF_DEG  184320000ull
#define OFF_RP   184960000ull
#define OFF_COL  185600032ull
#define OFF_NRM  189440032ull
#define OFF_O1F  190080032ull
#define OFF_U1F  190200032ull
#define OFF_O2F  190680032ull
#define OFF_U2F  191160032ull
#define OFF_WT   193080032ull   // 12 layers x [192 cols][576 k] fp16
// fp32 dim-3 temps alias the (not-yet-live) T1H region
#define OFF_X1F  OFF_T1H
#define OFF_X2F  (OFF_T1H + 1920000ull)

__device__ __forceinline__ float*  wsf(unsigned long long o){ return (float*) (g_ws + o); }
__device__ __forceinline__ int*    wsi(unsigned long long o){ return (int*)   (g_ws + o); }
__device__ __forceinline__ __half* wsh(unsigned long long o){ return (__half*)(g_ws + o); }

// ---------------- utility ----------------
__global__ void k_zero(unsigned long long off, int n) {
  int i = blockIdx.x*blockDim.x + threadIdx.x;
  if (i < n) wsi(off)[i] = 0;
}
__global__ void k_copyi(unsigned long long aOff, unsigned long long bOff, int n) {
  int i = blockIdx.x*blockDim.x + threadIdx.x;
  if (i < n) wsi(bOff)[i] = wsi(aOff)[i];
}

// ---------------- CSR build ----------------
__global__ void k_count_direct(const int* __restrict__ dst, int E) {
  int* deg = wsi(OFF_DEG);
  int e = blockIdx.x*blockDim.x + threadIdx.x;
  if (e < E) atomicAdd(&deg[dst[e]], 1);
}
__global__ void k_count_bidir(const int* __restrict__ edge, int E) {
  int* deg = wsi(OFF_DEG);
  int e = blockIdx.x*blockDim.x + threadIdx.x;
  if (e < E) {
    atomicAdd(&deg[edge[2*e+1]], 1);
    atomicAdd(&deg[edge[2*e  ]], 1);
  }
}
__global__ void k_norm(int n) {
  const int* deg = wsi(OFF_DEG);
  float* nrm = wsf(OFF_NRM);
  int i = blockIdx.x*blockDim.x + threadIdx.x;
  if (i < n) {
    int d = deg[i]; if (d < 1) d = 1;
    nrm[i] = rsqrtf((float)d);
  }
}
__global__ __launch_bounds__(1024) void k_exscan(int n) {
  const int* in = wsi(OFF_DEG);
  int* out = wsi(OFF_RP);
  __shared__ int sm[1024];
  int t = threadIdx.x;
  int carry = 0;
  for (int base = 0; base < n; base += 4096) {
    int idx = base + t*4;
    int v0 = (idx+0 < n) ? in[idx+0] : 0;
    int v1 = (idx+1 < n) ? in[idx+1] : 0;
    int v2 = (idx+2 < n) ? in[idx+2] : 0;
    int v3 = (idx+3 < n) ? in[idx+3] : 0;
    int s = v0+v1+v2+v3;
    sm[t] = s;
    __syncthreads();
    for (int off = 1; off < 1024; off <<= 1) {
      int u = (t >= off) ? sm[t-off] : 0;
      __syncthreads();
      sm[t] += u;
      __syncthreads();
    }
    int excl = carry + sm[t] - s;
    if (idx   < n) out[idx]   = excl;
    if (idx+1 < n) out[idx+1] = excl + v0;
    if (idx+2 < n) out[idx+2] = excl + v0+v1;
    if (idx+3 < n) out[idx+3] = excl + v0+v1+v2;
    carry += sm[1023];
    __syncthreads();
  }
  if (t == 0) out[n] = carry;
}
__global__ void k_fill_direct(const int* __restrict__ src, const int* __restrict__ dst, int E) {
  int* cur = wsi(OFF_DEG);
  int* col = wsi(OFF_COL);
  int e = blockIdx.x*blockDim.x + threadIdx.x;
  if (e < E) {
    int p = atomicAdd(&cur[dst[e]], 1);
    col[p] = src[e];
  }
}
__global__ void k_fill_bidir(const int* __restrict__ edge, int E) {
  int* cur = wsi(OFF_DEG);
  int* col = wsi(OFF_COL);
  int e = blockIdx.x*blockDim.x + threadIdx.x;
  if (e < E) {
    int u = edge[2*e], v = edge[2*e+1];
    int p = atomicAdd(&cur[v], 1); col[p] = u;
    int q = atomicAdd(&cur[u], 1); col[q] = v;
  }
}

// ---------------- propagation dim-3 (f32) ----------------
__global__ void k_spmm3(const float* __restrict__ Xext, unsigned long long Xoff,
                        unsigned long long Yoff, int n) {
  const float* X = Xext ? Xext : wsf(Xoff);
  float* Y = wsf(Yoff);
  const int* rowptr = wsi(OFF_RP);
  const int* col = wsi(OFF_COL);
  const float* nrm = wsf(OFF_NRM);
  int row = blockIdx.x*blockDim.x + threadIdx.x;
  if (row >= n) return;
  int s = rowptr[row], e = rowptr[row+1];
  float a0=0.f, a1=0.f, a2=0.f;
  for (int i = s; i < e; ++i) {
    int c = col[i]; float v = nrm[c];
    a0 = fmaf(v, X[c*3+0], a0);
    a1 = fmaf(v, X[c*3+1], a1);
    a2 = fmaf(v, X[c*3+2], a2);
  }
  float nm = nrm[row];
  Y[row*3+0] = a0*nm; Y[row*3+1] = a1*nm; Y[row*3+2] = a2*nm;
}

// ---------------- fp16 SpMM, half8 per lane, 24 lanes/row, 4-edge unrolled ----------------
__global__ __launch_bounds__(192) void k_spmm8(unsigned long long Xoff,
                                               unsigned long long Yoff, int n) {
  int gid = blockIdx.x*192 + threadIdx.x;
  if (gid >= n*24) return;
  int row = gid / 24, f8 = gid - row*24;
  const half8* __restrict__ X8 = (const half8*)wsh(Xoff);
  half8* __restrict__ Y8 = (half8*)wsh(Yoff);
  const int* rowptr = wsi(OFF_RP);
  const int* col = wsi(OFF_COL);
  const float* nrm = wsf(OFF_NRM);
  int s = rowptr[row], e = rowptr[row+1];
  float acc0[8], acc1[8];
  #pragma unroll
  for (int j = 0; j < 8; ++j) { acc0[j] = 0.f; acc1[j] = 0.f; }
  int i = s;
  for (; i + 4 <= e; i += 4) {
    int c0 = col[i], c1 = col[i+1], c2 = col[i+2], c3 = col[i+3];
    float w0 = nrm[c0], w1 = nrm[c1], w2 = nrm[c2], w3 = nrm[c3];
    half8 v0 = X8[(size_t)c0*24 + f8];
    half8 v1 = X8[(size_t)c1*24 + f8];
    half8 v2 = X8[(size_t)c2*24 + f8];
    half8 v3 = X8[(size_t)c3*24 + f8];
    #pragma unroll
    for (int j = 0; j < 8; ++j) {
      acc0[j] = fmaf(w0, (float)v0[j], acc0[j]);
      acc1[j] = fmaf(w1, (float)v1[j], acc1[j]);
      acc0[j] = fmaf(w2, (float)v2[j], acc0[j]);
      acc1[j] = fmaf(w3, (float)v3[j], acc1[j]);
    }
  }
  for (; i + 2 <= e; i += 2) {
    int c0 = col[i], c1 = col[i+1];
    float w0 = nrm[c0], w1 = nrm[c1];
    half8 v0 = X8[(size_t)c0*24 + f8];
    half8 v1 = X8[(size_t)c1*24 + f8];
    #pragma unroll
    for (int j = 0; j < 8; ++j) {
      acc0[j] = fmaf(w0, (float)v0[j], acc0[j]);
      acc1[j] = fmaf(w1, (float)v1[j], acc1[j]);
    }
  }
  if (i < e) {
    int c0 = col[i];
    float w0 = nrm[c0];
    half8 v0 = X8[(size_t)c0*24 + f8];
    #pragma unroll
    for (int j = 0; j < 8; ++j) acc0[j] = fmaf(w0, (float)v0[j], acc0[j]);
  }
  float nm = nrm[row];
  half8 r;
  #pragma unroll
  for (int j = 0; j < 8; ++j) r[j] = (_Float16)((acc0[j] + acc1[j])*nm);
  Y8[(size_t)row*24 + f8] = r;
}

// ---------------- first layer: [x|x1|x2](n,9)@Wf + b, relu -> H fp16 ----------------
__global__ void k_gemm_first(const float* __restrict__ xext, unsigned long long xOff,
                             const float* __restrict__ W, const float* __restrict__ b, int n) {
  const float* x  = xext ? xext : wsf(xOff);
  const float* x1 = wsf(OFF_X1F);
  const float* x2 = wsf(OFF_X2F);
  __half* H = wsh(OFF_HH);
  int idx = blockIdx.x*blockDim.x + threadIdx.x;
  if (idx >= n*HF) return;
  int row = idx / HF, c = idx - row*HF;
  float acc = b[c];
  #pragma unroll
  for (int k = 0; k < 3; ++k) acc = fmaf(x [row*3+k], W[(0+k)*HF + c], acc);
  #pragma unroll
  for (int k = 0; k < 3; ++k) acc = fmaf(x1[row*3+k], W[(3+k)*HF + c], acc);
  #pragma unroll
  for (int k = 0; k < 3; ++k) acc = fmaf(x2[row*3+k], W[(6+k)*HF + c], acc);
  H[idx] = __float2half(fmaxf(acc, 0.f));
}

// ---------------- W prep: Wt[it][col][k] = fp16(Wm[stage it][k][col]) ----------------
__global__ void k_wprep(const float* __restrict__ Wm, int s) {
  int idx = blockIdx.x*blockDim.x + threadIdx.x;
  if (idx >= 12*576*HF) return;
  int it = idx / (576*HF);
  int rem = idx - it*576*HF;
  int k = rem / HF;
  int c = rem - k*HF;
  wsh(OFF_WT)[(size_t)it*HF*576 + (size_t)c*576 + k] =
      __float2half(Wm[((size_t)(s*12+it)*576 + k)*HF + c]);
}

// ---------------- MFMA mid layer, 64 rows/block, LDS-staged B (r19-proven) ----------------
#define BPAD 104
__global__ __launch_bounds__(256) void k_mfma_mid(
    const float* __restrict__ b, int it, int n, int residual)
{
  __half* __restrict__ H = wsh(OFF_HH);
  const __half* __restrict__ T1 = wsh(OFF_T1H);
  const __half* __restrict__ T2 = wsh(OFF_T2H);
  const __half* __restrict__ Wt = wsh(OFF_WT) + (size_t)it*HF*576;
  __shared__ _Float16 Bs[192*BPAD];   // 39,936 B
  int t = threadIdx.x;
  int w = t >> 6;
  int l = t & 63;
  int lr = l & 15;
  int lg = l >> 4;
  int row0 = blockIdx.x*64 + w*16;

  f32x4 acc[12];
  #pragma unroll
  for (int i = 0; i < 12; ++i) acc[i] = (f32x4){0.f,0.f,0.f,0.f};

  const __half* Xp[3] = { H, T1, T2 };
  for (int p = 0; p < 3; ++p) {
    const __half* X = Xp[p];
    for (int kh = 0; kh < 2; ++kh) {
      __syncthreads();
      for (int i = t; i < 192*12; i += 256) {
        int c  = i / 12;
        int k8 = i - c*12;
        *(half8*)&Bs[c*BPAD + k8*8] =
            *(const half8*)&Wt[(size_t)c*576 + p*HF + kh*96 + k8*8];
      }
      __syncthreads();
      #pragma unroll
      for (int k0 = 0; k0 < 96; k0 += 32) {
        half8 a = *(const half8*)&X[(size_t)(row0 + lr)*HF + kh*96 + k0 + lg*8];
        #pragma unroll
        for (int tl = 0; tl < 12; ++tl) {
          half8 bb = *(const half8*)&Bs[(tl*16 + lr)*BPAD + k0 + lg*8];
          acc[tl] = __builtin_amdgcn_mfma_f32_16x16x32_f16(a, bb, acc[tl], 0, 0, 0);
        }
      }
    }
  }

  #pragma unroll
  for (int tl = 0; tl < 12; ++tl) {
    int c = tl*16 + lr;
    float bias = b[c];
    #pragma unroll
    for (int j = 0; j < 4; ++j) {
      int row = row0 + lg*4 + j;
      if (row < n) {
        size_t o = (size_t)row*HF + c;
        float cur = fmaxf(acc[tl][j] + bias, 0.f);
        float h = cur;
        if (residual) h = 0.5f*(__half2float(H[o]) + cur);
        H[o] = __float2half(h);
      }
    }
  }
}

// ---------------- last layer (vectorized linear reads) ----------------
__global__ void k_last_lin(const float* __restrict__ W, const float* __restrict__ b,
                           float* __restrict__ outb, unsigned long long outfOff,
                           int hasOutf, int n) {
  int row = blockIdx.x*blockDim.x + threadIdx.x;
  if (row >= n) return;
  const __half* bufs[3] = { wsh(OFF_HH), wsh(OFF_T1H), wsh(OFF_T2H) };
  float a0 = b[0], a1 = b[1], a2 = b[2];
  for (int p = 0; p < 3; ++p) {
    const half8* x8 = (const half8*)&bufs[p][(size_t)row*HF];
    #pragma unroll 4
    for (int k8 = 0; k8 < 24; ++k8) {
      half8 v = x8[k8];
      #pragma unroll
      for (int j = 0; j < 8; ++j) {
        int k = k8*8 + j;
        const float* w = &W[(p*HF + k)*3];
        float vv = (float)v[j];
        a0 = fmaf(vv, w[0], a0); a1 = fmaf(vv, w[1], a1); a2 = fmaf(vv, w[2], a2);
      }
    }
  }
  outb[row*3+0] = a0;
  outb[row*3+1] = a1;
  outb[row*3+2] = a2;
  if (hasOutf) {
    float* outf = wsf(outfOff);
    outf[row*3+0] = a0; outf[row*3+1] = a1; outf[row*3+2] = a2;
  }
}

// ---------------- unpool ----------------
__global__ void k_unpool(unsigned long long srcOff, const int* __restrict__ pidx,
                         unsigned long long dstfOff, float* __restrict__ dstb,
                         int n, int P) {
  const float* src = wsf(srcOff);
  float* dstf = wsf(dstfOff);
  int i = blockIdx.x*blockDim.x + threadIdx.x;
  if (i >= n + P) return;
  float v0, v1, v2;
  if (i < n) {
    v0 = src[i*3+0]; v1 = src[i*3+1]; v2 = src[i*3+2];
  } else {
    int a = pidx[(i-n)*2], c = pidx[(i-n)*2+1];
    v0 = 0.5f*(src[a*3+0] + src[c*3+0]);
    v1 = 0.5f*(src[a*3+1] + src[c*3+1]);
    v2 = 0.5f*(src[a*3+2] + src[c*3+2]);
  }
  dstf[i*3+0] = v0; dstf[i*3+1] = v1; dstf[i*3+2] = v2;
  dstb[i*3+0] = v0;
  dstb[i*3+1] = v1;
  dstb[i*3+2] = v2;
}

extern "C" void kernel_launch(void* const* d_in, const int* in_sizes, int n_in,
                              void* d_out, int out_size, void* d_ws, size_t ws_size,
                              hipStream_t stream) {
  (void)in_sizes; (void)n_in; (void)out_size; (void)d_ws; (void)ws_size;
  const float* features = (const float*)d_in[0];
  const int*  src0  = (const int*)d_in[1];
  const int*  dst0  = (const int*)d_in[2];
  const int*  pool0 = (const int*)d_in[3];
  const int*  edge0 = (const int*)d_in[4];
  const int*  pool1 = (const int*)d_in[5];
  const int*  edge1 = (const int*)d_in[6];
  const float* Wf = (const float*)d_in[7];
  const float* bfp = (const float*)d_in[8];
  const float* Wm = (const float*)d_in[9];
  const float* bm = (const float*)d_in[10];
  const float* Wl = (const float*)d_in[11];
  const float* bl = (const float*)d_in[12];
  float* out = (float*)d_out;

  auto csr = [&](int n, const int* srcD, const int* dstD, int Edir,
                 const int* edgeB, int Eund) {
    k_zero<<<divup(n,256),256,0,stream>>>(OFF_DEG, n);
    if (srcD) k_count_direct<<<divup(Edir,256),256,0,stream>>>(dstD, Edir);
    else      k_count_bidir <<<divup(Eund,256),256,0,stream>>>(edgeB, Eund);
    k_norm<<<divup(n,256),256,0,stream>>>(n);
    k_exscan<<<1,1024,0,stream>>>(n);
    k_copyi<<<divup(n,256),256,0,stream>>>(OFF_RP, OFF_DEG, n);
    if (srcD) k_fill_direct<<<divup(Edir,256),256,0,stream>>>(srcD, dstD, Edir);
    else      k_fill_bidir <<<divup(Eund,256),256,0,stream>>>(edgeB, Eund);
  };

  auto stage_u = [&](const float* xext, unsigned long long xOff, int n,
                     const int* srcD, const int* dstD, int Edir,
                     const int* edgeB, int Eund,
                     int s, float* outb, unsigned long long outfOff, int hasOutf) {
    csr(n, srcD, dstD, Edir, edgeB, Eund);
    k_wprep<<<divup(12*576*HF,256),256,0,stream>>>(Wm, s);
    k_spmm3<<<divup(n,256),256,0,stream>>>(xext, xOff, OFF_X1F, n);
    k_spmm3<<<divup(n,256),256,0,stream>>>(nullptr, OFF_X1F, OFF_X2F, n);
    k_gemm_first<<<divup(n*HF,256),256,0,stream>>>(xext, xOff,
        Wf + (size_t)s*9*HF, bfp + s*HF, n);
    int gsp = divup(n*24,192);
    for (int it = 0; it < 12; ++it) {
      k_spmm8<<<gsp,192,0,stream>>>(OFF_HH,  OFF_T1H, n);
      k_spmm8<<<gsp,192,0,stream>>>(OFF_T1H, OFF_T2H, n);
      k_mfma_mid<<<divup(n,64),256,0,stream>>>(bm + (s*12+it)*HF, it, n,
          ((it+1)%2==0) ? 1 : 0);
    }
    k_spmm8<<<gsp,192,0,stream>>>(OFF_HH,  OFF_T1H, n);
    k_spmm8<<<gsp,192,0,stream>>>(OFF_T1H, OFF_T2H, n);
    k_last_lin<<<divup(n,256),256,0,stream>>>(Wl + (size_t)s*576*3, bl + s*3,
        outb, outfOff, hasOutf, n);
  };

  // stage 1: n=10000, direct edges
  stage_u(features, 0ull, 10000, src0, dst0, 60000, nullptr, 0,
          0, out + 0, OFF_O1F, 1);
  k_unpool<<<divup(40000,256),256,0,stream>>>(OFF_O1F, pool0, OFF_U1F, out + 630000, 10000, 30000);
  // stage 2: n=40000, bidir edge0
  stage_u(nullptr, OFF_U1F, 40000, nullptr, nullptr, 0, edge0, 120000,
          1, out + 30000, OFF_O2F, 1);
  k_unpool<<<divup(160000,256),256,0,stream>>>(OFF_O2F, pool1, OFF_U2F, out + 750000, 40000, 120000);
  // stage 3: n=160000, bidir edge1
  stage_u(nullptr, OFF_U2F, 160000, nullptr, nullptr, 0, edge1, 480000,
          2, out + 150000, OFF_O1F, 0);
}